// Round 5
// baseline (9761.462 us; speedup 1.0000x reference)
//
#include <hip/hip_runtime.h>
#include <stdint.h>

#define TS   1024
#define NB   32
#define DIN  512
#define HU   768
#define NWG  32          // workgroups per direction
#define UPW  24          // hidden units per WG
#define APAD 1288        // As row stride in fp16 (1280+8)
#define HB64 8192        // u64 words per h buffer (32 rows x 256)
#define SPIN_MAX (1 << 16)

typedef _Float16 f16x8 __attribute__((ext_vector_type(8)));
typedef float f32x16 __attribute__((ext_vector_type(16)));
typedef unsigned int u32;
typedef unsigned long long u64;
typedef u32 u32x4 __attribute__((ext_vector_type(4)));

__device__ __forceinline__ u32 f2h_bits(float f) {
  _Float16 h = (_Float16)f;
  return (u32)__builtin_bit_cast(unsigned short, h);
}

// ---------------- init: zero ALL 4 h buffers (fw/bw x ping/pong) ----------------
// h(0)=0 with tag 0; also clears stale tags from previous graph replays.
__global__ void lstm_init_k(u32* hb) {
  hb[blockIdx.x * 256 + threadIdx.x] = 0u;   // grid 256 x 256 = 65536 u32 = 512 KB/2... 4x64KB
}

// ---------------- transpose + fp16 convert: x[B][T][D] -> xh[T][B][D] ----------------
__global__ void lstm_xpose_k(const float* __restrict__ x, unsigned short* __restrict__ xh) {
  int idx = blockIdx.x * 256 + threadIdx.x;
  int d4 = idx & 127;
  int t  = (idx >> 7) & 1023;
  int b  = idx >> 17;
  float4 v = *(const float4*)(x + ((size_t)(b * TS + t) * DIN + d4 * 4));
  ushort4 o;
  o.x = (unsigned short)f2h_bits(v.x); o.y = (unsigned short)f2h_bits(v.y);
  o.z = (unsigned short)f2h_bits(v.z); o.w = (unsigned short)f2h_bits(v.w);
  *(ushort4*)(xh + ((size_t)(t * NB + b) * DIN + d4 * 4)) = o;
}

#define BAR_LGKM() do { asm volatile("s_waitcnt lgkmcnt(0)" ::: "memory"); \
  __builtin_amdgcn_sched_barrier(0); __builtin_amdgcn_s_barrier(); \
  __builtin_amdgcn_sched_barrier(0); } while (0)

// ---------------- persistent bidirectional LSTM scan (64 blocks, no global barrier) ----------------
__global__ __launch_bounds__(256, 1) void lstm_persist_k(
    const float* __restrict__ Wfw, const float* __restrict__ bfw, const float* __restrict__ pfw,
    const float* __restrict__ Wbw, const float* __restrict__ bbw, const float* __restrict__ pbw,
    const unsigned short* __restrict__ xh,
    u64* hb, float* __restrict__ out)
{
  __shared__ __align__(16) unsigned short As[NB * APAD];   // 82,432 B
  __shared__ __align__(16) float Zs[4][NB][100];           // 51,200 B

  const int tid = threadIdx.x;
  const int dir = (blockIdx.x >= NWG) ? 1 : 0;
  const int gg  = blockIdx.x & (NWG - 1);

  const float* W    = dir ? Wbw : Wfw;
  const float* bias = dir ? bbw : bfw;
  const float* peep = dir ? pbw : pfw;
  u64* hbuf = hb + dir * 2 * HB64;
  const int u0 = gg * UPW;

  const int lane  = tid & 63;
  const int wq    = tid >> 6;      // wave id = K-quarter
  const int colc  = lane & 31;
  const int khalf = lane >> 5;
  const int arow  = colc;          // A-frag row = batch
  const int hrow  = tid >> 3;      // h staging / epilogue row (0..31)
  const int eb    = tid >> 3;
  const int ep    = tid & 7;       // phase within row

  // ---- preload W slice: 3 col-tiles x 20 K-slices (240 VGPR) ----
  // tile ct, local col c: gate = c&3, unit = u0 + 8*ct + (c>>2)
  f16x8 wfr[3][20];
#pragma unroll
  for (int ct = 0; ct < 3; ++ct) {
    const int gcol = (colc & 3) * HU + u0 + 8 * ct + (colc >> 2);
#pragma unroll
    for (int ks = 0; ks < 20; ++ks) {
      const int k0 = wq * 320 + ks * 16 + khalf * 8;
#pragma unroll
      for (int j = 0; j < 8; ++j)
        wfr[ct][ks][j] = (_Float16)W[(size_t)(k0 + j) * 3072 + gcol];
    }
  }

  // ---- per-thread epilogue constants: 3 CONTIGUOUS units U = u0 + 3*ep + q ----
  float bi[3], bj[3], bfc[3], bo[3], pi[3], pfc[3], po[3], cst[3];
#pragma unroll
  for (int q = 0; q < 3; ++q) {
    const int U = u0 + 3 * ep + q;
    bi[q] = bias[U]; bj[q] = bias[HU + U]; bfc[q] = bias[2 * HU + U]; bo[q] = bias[3 * HU + U];
    pi[q] = peep[U]; pfc[q] = peep[HU + U]; po[q] = peep[2 * HU + U];
    cst[q] = 0.0f;
  }

  // ---- prologue: x(t0) -> LDS ----
  {
    const unsigned short* x0 = xh + (size_t)(dir ? (TS - 1) : 0) * (NB * DIN);
    u32x4 t[8];
#pragma unroll
    for (int k = 0; k < 8; ++k) t[k] = *(const u32x4*)(x0 + (tid + 256 * k) * 8);
#pragma unroll
    for (int k = 0; k < 8; ++k) {
      const int idx = tid + 256 * k;
      *(u32x4*)(&As[(idx >> 6) * APAD + (idx & 63) * 8]) = t[k];
    }
  }

  u32x4 xr[8];           // x prefetch for step s+1
  float hnPrev[3] = {0.f, 0.f, 0.f};
  int   tPrev = 0;

  for (int s = 0; s < TS; ++s) {
    const int t_in = dir ? (TS - 1 - s) : s;
    const u64* hsrc = hbuf + (s & 1) * HB64;
    u64*       hdst = hbuf + (((s + 1) & 1)) * HB64;

    // ---- P2: tagged h(s) load (retry until tag==s), 32 coalesced u64/thread ----
    u64 v[32];
    {
      const u64* bp = hsrc + hrow * 256 + ep * 32;
      int it = 0; bool ok;
      do {
#pragma unroll
        for (int k = 0; k < 32; ++k)
          v[k] = __hip_atomic_load(bp + k, __ATOMIC_RELAXED, __HIP_MEMORY_SCOPE_AGENT);
        u32 bad = 0;
#pragma unroll
        for (int k = 0; k < 32; ++k) bad |= (u32)(v[k] >> 48) ^ (u32)s;
        ok = __all(bad == 0);
      } while (!ok && ++it < SPIN_MAX);
    }
    // reassemble 32 x {3 fp16} -> 96 fp16 -> LDS h region (units 96*ep .. +95)
    {
      char* dst = (char*)&As[hrow * APAD + 512 + ep * 96];
#pragma unroll
      for (int gq = 0; gq < 4; ++gq) {
        u32 w[12];
#pragma unroll
        for (int j = 0; j < 4; ++j) {
          const u64 a = v[8 * gq + 2 * j], b = v[8 * gq + 2 * j + 1];
          w[3 * j]     = (u32)a;
          w[3 * j + 1] = ((u32)(a >> 32) & 0xFFFFu) | ((u32)b << 16);
          w[3 * j + 2] = (u32)(b >> 16);
        }
        u32x4* d4 = (u32x4*)(dst + gq * 48);
        d4[0] = u32x4{w[0], w[1], w[2],  w[3]};
        d4[1] = u32x4{w[4], w[5], w[6],  w[7]};
        d4[2] = u32x4{w[8], w[9], w[10], w[11]};
      }
    }
    BAR_LGKM();   // As = [x(t_s) | h(s)] complete

    // ---- lagged out store for step s-1 (acks hide under MFMA) ----
    if (s > 0) {
#pragma unroll
      for (int q = 0; q < 3; ++q)
        __builtin_nontemporal_store(hnPrev[q],
            out + ((size_t)eb * TS + tPrev) * 1536 + dir * HU + u0 + 3 * ep + q);
    }

    // ---- P3: MFMA, 3 col-tiles over this wave's K-quarter ----
    f32x16 a0, a1, a2;
#pragma unroll
    for (int r = 0; r < 16; ++r) { a0[r] = 0.f; a1[r] = 0.f; a2[r] = 0.f; }
#pragma unroll
    for (int ks = 0; ks < 20; ++ks) {
      const int kc = wq * 40 + ks * 2 + khalf;
      const f16x8 av = *(const f16x8*)(&As[arow * APAD + kc * 8]);
      a0 = __builtin_amdgcn_mfma_f32_32x32x16_f16(av, wfr[0][ks], a0, 0, 0, 0);
      a1 = __builtin_amdgcn_mfma_f32_32x32x16_f16(av, wfr[1][ks], a1, 0, 0, 0);
      a2 = __builtin_amdgcn_mfma_f32_32x32x16_f16(av, wfr[2][ks], a2, 0, 0, 0);
    }

    // ---- P4: prefetch x(s+1) ----
    if (s + 1 < TS) {
      const int t_next = dir ? (TS - 2 - s) : (s + 1);
      const unsigned short* xnb = xh + (size_t)t_next * (NB * DIN);
#pragma unroll
      for (int k = 0; k < 8; ++k) xr[k] = *(const u32x4*)(xnb + (tid + 256 * k) * 8);
    }

    // ---- P5: partial z -> LDS; C/D layout col=lane&31, row=(r&3)+8*(r>>2)+4*khalf ----
#pragma unroll
    for (int r = 0; r < 16; ++r) {
      const int prow = (r & 3) + 8 * (r >> 2) + 4 * khalf;
      Zs[wq][prow][colc]      = a0[r];
      Zs[wq][prow][32 + colc] = a1[r];
      Zs[wq][prow][64 + colc] = a2[r];
    }
    BAR_LGKM();   // Zs ready; all As reads done

    // ---- P6: epilogue, 3 contiguous cells ----
    float hn[3];
#pragma unroll
    for (int q = 0; q < 3; ++q) {
      const int uu = 3 * ep + q;
      float zi = 0.f, zj = 0.f, zf = 0.f, zo = 0.f;
#pragma unroll
      for (int qq = 0; qq < 4; ++qq) {
        const float4 zp = *(const float4*)(&Zs[qq][eb][uu * 4]);
        zi += zp.x; zj += zp.y; zf += zp.z; zo += zp.w;
      }
      const float ig = 1.f / (1.f + __expf(-(zi + bi[q] + pi[q] * cst[q])));
      const float fg = 1.f / (1.f + __expf(-(zf + bfc[q] + 1.f + pfc[q] * cst[q])));
      const float jt = 1.f - 2.f / (__expf(2.f * (zj + bj[q])) + 1.f);
      const float cn = fg * cst[q] + ig * jt;
      const float og = 1.f / (1.f + __expf(-(zo + bo[q] + po[q] * cn)));
      hn[q] = og * (1.f - 2.f / (__expf(2.f * cn) + 1.f));
      cst[q] = cn;
    }

    if (s < TS - 1) {
      // ---- tagged h(s+1) publish: one 8B atomic store (data+tag fused) ----
      const u32 h01 = f2h_bits(hn[0]) | (f2h_bits(hn[1]) << 16);
      const u32 h2t = f2h_bits(hn[2]) | (((u32)(s + 1)) << 16);
      __hip_atomic_store(hdst + eb * 256 + 8 * gg + ep,
                         ((u64)h2t << 32) | (u64)h01,
                         __ATOMIC_RELAXED, __HIP_MEMORY_SCOPE_AGENT);

      // ---- P1: staged x(s+1) -> LDS ----
#pragma unroll
      for (int k = 0; k < 8; ++k) {
        const int idx = tid + 256 * k;
        *(u32x4*)(&As[(idx >> 6) * APAD + (idx & 63) * 8]) = xr[k];
      }
    }

#pragma unroll
    for (int q = 0; q < 3; ++q) hnPrev[q] = hn[q];
    tPrev = t_in;
  }

  // final out store (step TS-1)
#pragma unroll
  for (int q = 0; q < 3; ++q)
    __builtin_nontemporal_store(hnPrev[q],
        out + ((size_t)eb * TS + tPrev) * 1536 + dir * HU + u0 + 3 * ep + q);
}

extern "C" void kernel_launch(void* const* d_in, const int* in_sizes, int n_in,
                              void* d_out, int out_size, void* d_ws, size_t ws_size,
                              hipStream_t stream) {
  const float* x   = (const float*)d_in[0];
  const float* Wfw = (const float*)d_in[1];
  const float* bfw = (const float*)d_in[2];
  const float* pfw = (const float*)d_in[3];
  const float* Wbw = (const float*)d_in[4];
  const float* bbw = (const float*)d_in[5];
  const float* pbw = (const float*)d_in[6];
  float* out = (float*)d_out;

  char* ws = (char*)d_ws;
  unsigned short* xh = (unsigned short*)ws;              // 33,554,432 B
  u64* hb            = (u64*)(ws + 33554432);            //    262,144 B (4 x 64 KB)

  lstm_init_k<<<256, 256, 0, stream>>>((u32*)hb);        // zero all 4 h buffers
  lstm_xpose_k<<<16384, 256, 0, stream>>>(x, xh);
  lstm_persist_k<<<dim3(2 * NWG), dim3(256), 0, stream>>>(Wfw, bfw, pfw, Wbw, bbw, pbw,
                                                          xh, hb, out);
}

// Round 7
// 7091.240 us; speedup vs baseline: 1.3766x; 1.3766x over previous
//
#include <hip/hip_runtime.h>
#include <stdint.h>

#define TS   1024
#define NB   32
#define DIN  512
#define HU   768
#define NWG  32          // workgroups per direction
#define UPW  24          // hidden units per WG
#define XPAD 520         // x-region LDS row stride in fp16 (512 + 8)
#define SPIN_MAX 16384

typedef _Float16 f16x8 __attribute__((ext_vector_type(8)));
typedef float f32x16 __attribute__((ext_vector_type(16)));
typedef unsigned int u32;
typedef unsigned long long u64;
typedef u32 u32x4 __attribute__((ext_vector_type(4)));
typedef u64 u64x2 __attribute__((ext_vector_type(2)));

__device__ __forceinline__ u32 f2h_bits(float f) {
  _Float16 h = (_Float16)f;
  return (u32)__builtin_bit_cast(unsigned short, h);
}

// ---------------- init: zero h buffers (buf0 of each dir) + ALL 512 ctrl words ----------------
// (R4 bug fix: grid 99 covers 2*12288 + 512 = 25088 words; counters are cumulative per
//  launch, so replay-safety requires re-zeroing every used counter.)
__global__ void lstm_init_k(u32* hb_fw, u32* hb_bw, u32* ctrl) {
  int i = blockIdx.x * 256 + threadIdx.x;
  const int HB = NB * HU / 2;            // 12288 u32 per h buffer0
  if (i < HB) hb_fw[i] = 0u;
  else if (i < 2 * HB) hb_bw[i - HB] = 0u;
  else if (i < 2 * HB + 512) ctrl[i - 2 * HB] = 0u;
}

// ---------------- transpose + fp16 convert: x[B][T][D] -> xh[T][B][D] ----------------
__global__ void lstm_xpose_k(const float* __restrict__ x, unsigned short* __restrict__ xh) {
  int idx = blockIdx.x * 256 + threadIdx.x;
  int d4 = idx & 127;
  int t  = (idx >> 7) & 1023;
  int b  = idx >> 17;
  float4 v = *(const float4*)(x + ((size_t)(b * TS + t) * DIN + d4 * 4));
  ushort4 o;
  o.x = (unsigned short)f2h_bits(v.x); o.y = (unsigned short)f2h_bits(v.y);
  o.z = (unsigned short)f2h_bits(v.z); o.w = (unsigned short)f2h_bits(v.w);
  *(ushort4*)(xh + ((size_t)(t * NB + b) * DIN + d4 * 4)) = o;
}

#define BAR_LGKM() do { asm volatile("s_waitcnt lgkmcnt(0)" ::: "memory"); \
  __builtin_amdgcn_sched_barrier(0); __builtin_amdgcn_s_barrier(); \
  __builtin_amdgcn_sched_barrier(0); } while (0)
#define BAR_VM0() do { asm volatile("s_waitcnt vmcnt(0) lgkmcnt(0)" ::: "memory"); \
  __builtin_amdgcn_sched_barrier(0); __builtin_amdgcn_s_barrier(); \
  __builtin_amdgcn_sched_barrier(0); } while (0)

// ---------------- persistent bidirectional LSTM scan (64 blocks, plain launch) ----------------
__global__ __launch_bounds__(256, 1) void lstm_persist_k(
    const float* __restrict__ Wfw, const float* __restrict__ bfw, const float* __restrict__ pfw,
    const float* __restrict__ Wbw, const float* __restrict__ bbw, const float* __restrict__ pbw,
    const unsigned short* __restrict__ xh,
    unsigned short* hb_fw, unsigned short* hb_bw,
    u32* ctrl, float* __restrict__ out)
{
  __shared__ __align__(16) unsigned short As[NB * XPAD];   // 33,280 B (x tile only)
  __shared__ __align__(16) float Zs[4][NB][100];           // 51,200 B

  const int tid = threadIdx.x;
  const int dir = (blockIdx.x >= NWG) ? 1 : 0;
  const int gg  = blockIdx.x & (NWG - 1);

  const float* W    = dir ? Wbw : Wfw;
  const float* bias = dir ? bbw : bfw;
  const float* peep = dir ? pbw : pfw;
  unsigned short* hbuf = dir ? hb_bw : hb_fw;
  u32* cnt = ctrl + 16 + dir * 128;       // 8 group counters, 64B apart
  const int u0 = gg * UPW;

  const int lane  = tid & 63;
  const int wq    = tid >> 6;      // wave id
  const int colc  = lane & 31;
  const int khalf = lane >> 5;
  const int arow  = colc;          // A-frag row = batch
  const int eb    = tid >> 3;      // epilogue batch row
  const int ep    = tid & 7;       // epilogue unit phase

  // ---- preload W: 3 col-tiles x 20 K-slices; K-stripe c = 8m + 4*khalf + wq ----
  // tile ct, local col c: gate = c&3, unit = u0 + 8*ct + (c>>2)
  f16x8 wfr[3][20];
#pragma unroll
  for (int ct = 0; ct < 3; ++ct) {
    const int gcol = (colc & 3) * HU + u0 + 8 * ct + (colc >> 2);
#pragma unroll
    for (int m = 0; m < 20; ++m) {
      const int k0 = (8 * m + 4 * khalf + wq) * 8;
#pragma unroll
      for (int j = 0; j < 8; ++j)
        wfr[ct][m][j] = (_Float16)W[(size_t)(k0 + j) * 3072 + gcol];
    }
  }

  // ---- per-thread epilogue constants: units U = u0 + ep + 8q ----
  float bi[3], bj[3], bfc[3], bo[3], pi[3], pfc[3], po[3], cst[3];
#pragma unroll
  for (int q = 0; q < 3; ++q) {
    const int U = u0 + ep + 8 * q;
    bi[q] = bias[U]; bj[q] = bias[HU + U]; bfc[q] = bias[2 * HU + U]; bo[q] = bias[3 * HU + U];
    pi[q] = peep[U]; pfc[q] = peep[HU + U]; po[q] = peep[2 * HU + U];
    cst[q] = 0.0f;
  }

  // ---- prologue: x(t0) -> LDS ----
  {
    const unsigned short* x0 = xh + (size_t)(dir ? (TS - 1) : 0) * (NB * DIN);
    u32x4 t[8];
#pragma unroll
    for (int k = 0; k < 8; ++k) t[k] = *(const u32x4*)(x0 + (tid + 256 * k) * 8);
#pragma unroll
    for (int k = 0; k < 8; ++k) {
      const int idx = tid + 256 * k;
      *(u32x4*)(&As[(idx >> 6) * XPAD + (idx & 63) * 8]) = t[k];
    }
  }
  BAR_LGKM();

  u32x4 xr[8];   // x prefetch registers for step s+1

  for (int s = 0; s < TS; ++s) {
    const int t_in = dir ? (TS - 1 - s) : s;
    const u64* hsrc64 = (const u64*)(hbuf + (s & 1) * (NB * HU));
    u32* hnext32 = (u32*)(hbuf + (((s & 1) ^ 1)) * (NB * HU));

    // ---- issue h(s) A-fragment loads directly to registers (agent scope, proven) ----
    u64 hv[24];
#pragma unroll
    for (int m = 8; m < 20; ++m) {
      const int c = 8 * m + 4 * khalf + wq;            // 64..159
      const int i64 = arow * 192 + (c - 64) * 2;
      hv[2 * (m - 8)]     = __hip_atomic_load(hsrc64 + i64,
                                              __ATOMIC_RELAXED, __HIP_MEMORY_SCOPE_AGENT);
      hv[2 * (m - 8) + 1] = __hip_atomic_load(hsrc64 + i64 + 1,
                                              __ATOMIC_RELAXED, __HIP_MEMORY_SCOPE_AGENT);
    }
    __builtin_amdgcn_sched_barrier(0);

    // ---- x-tile MFMAs (LDS, staged last step) hide the h-load latency ----
    f32x16 a0, a1, a2;
#pragma unroll
    for (int r = 0; r < 16; ++r) { a0[r] = 0.f; a1[r] = 0.f; a2[r] = 0.f; }
#pragma unroll
    for (int m = 0; m < 8; ++m) {
      const int c = 8 * m + 4 * khalf + wq;
      const f16x8 av = *(const f16x8*)(&As[arow * XPAD + c * 8]);
      a0 = __builtin_amdgcn_mfma_f32_32x32x16_f16(av, wfr[0][m], a0, 0, 0, 0);
      a1 = __builtin_amdgcn_mfma_f32_32x32x16_f16(av, wfr[1][m], a1, 0, 0, 0);
      a2 = __builtin_amdgcn_mfma_f32_32x32x16_f16(av, wfr[2][m], a2, 0, 0, 0);
    }

    // ---- h MFMAs from registers ----
#pragma unroll
    for (int m = 8; m < 20; ++m) {
      u64x2 t; t[0] = hv[2 * (m - 8)]; t[1] = hv[2 * (m - 8) + 1];
      const f16x8 av = __builtin_bit_cast(f16x8, t);
      a0 = __builtin_amdgcn_mfma_f32_32x32x16_f16(av, wfr[0][m], a0, 0, 0, 0);
      a1 = __builtin_amdgcn_mfma_f32_32x32x16_f16(av, wfr[1][m], a1, 0, 0, 0);
      a2 = __builtin_amdgcn_mfma_f32_32x32x16_f16(av, wfr[2][m], a2, 0, 0, 0);
    }

    // ---- prefetch x(s+1) into registers (drains at BAR_VM0) ----
    if (s + 1 < TS) {
      const int t_next = dir ? (TS - 2 - s) : (s + 1);
      const unsigned short* xnb = xh + (size_t)t_next * (NB * DIN);
#pragma unroll
      for (int k = 0; k < 8; ++k) xr[k] = *(const u32x4*)(xnb + (tid + 256 * k) * 8);
    }

    // ---- partial z -> LDS; C/D layout: col=lane&31, row=(r&3)+8*(r>>2)+4*khalf ----
#pragma unroll
    for (int r = 0; r < 16; ++r) {
      const int prow = (r & 3) + 8 * (r >> 2) + 4 * khalf;
      Zs[wq][prow][colc]      = a0[r];
      Zs[wq][prow][32 + colc] = a1[r];
      Zs[wq][prow][64 + colc] = a2[r];
    }
    BAR_LGKM();   // Zs ready

    // ---- epilogue: 3 cells per thread (row eb, units u0+ep+8q) ----
    float hn[3];
#pragma unroll
    for (int q = 0; q < 3; ++q) {
      const int uu = ep + 8 * q;
      float zi = 0.f, zj = 0.f, zf = 0.f, zo = 0.f;
#pragma unroll
      for (int qq = 0; qq < 4; ++qq) {
        const float4 zp = *(const float4*)(&Zs[qq][eb][uu * 4]);
        zi += zp.x; zj += zp.y; zf += zp.z; zo += zp.w;
      }
      const float ig = 1.f / (1.f + __expf(-(zi + bi[q] + pi[q] * cst[q])));
      const float fg = 1.f / (1.f + __expf(-(zf + bfc[q] + 1.f + pfc[q] * cst[q])));
      const float jt = 1.f - 2.f / (__expf(2.f * (zj + bj[q])) + 1.f);
      const float cn = fg * cst[q] + ig * jt;
      const float og = 1.f / (1.f + __expf(-(zo + bo[q] + po[q] * cn)));
      hn[q] = og * (1.f - 2.f / (__expf(2.f * cn) + 1.f));
      cst[q] = cn;
    }

    if (s < TS - 1) {
      // ---- publish h(s+1): pack fp16 pairs, agent-scope u32 stores (R4-proven) ----
#pragma unroll
      for (int q = 0; q < 3; ++q) {
        const u32 mine  = f2h_bits(hn[q]);
        const u32 other = (u32)(unsigned)__shfl_xor((int)mine, 1, 64);
        if (!(tid & 1)) {
          __hip_atomic_store(hnext32 + ((eb * HU + u0 + ep + 8 * q) >> 1),
                             mine | (other << 16),
                             __ATOMIC_RELAXED, __HIP_MEMORY_SCOPE_AGENT);
        }
      }
      BAR_VM0();      // h stores acked at MALL; hv/xr loads + prev out stores drained

      // arrive: one fire-and-forget agent add per WG (8 counters/dir, 64B apart)
      if (tid == 0)
        (void)__hip_atomic_fetch_add(&cnt[(gg >> 2) * 16], 1u,
                                     __ATOMIC_RELAXED, __HIP_MEMORY_SCOPE_AGENT);

      // out stores off the critical path (drained at next step's BAR_VM0)
#pragma unroll
      for (int q = 0; q < 3; ++q)
        __builtin_nontemporal_store(hn[q],
            out + ((size_t)eb * TS + t_in) * 1536 + dir * HU + u0 + ep + 8 * q);

      // staged x(s+1) regs -> LDS (As reads finished at Zs barrier)
#pragma unroll
      for (int k = 0; k < 8; ++k) {
        const int idx = tid + 256 * k;
        *(u32x4*)(&As[(idx >> 6) * XPAD + (idx & 63) * 8]) = xr[k];
      }

      // release poll: wave 0, lanes 0..7 poll 8 group counters in parallel (bounded)
      if (wq == 0) {
        const u32 need = 4u * (u32)(s + 1);
        int it = 0; bool ok;
        do {
          u32 v = need;
          if (lane < 8)
            v = __hip_atomic_load(&cnt[lane * 16], __ATOMIC_RELAXED, __HIP_MEMORY_SCOPE_AGENT);
          ok = __all((int)(v >= need));
          if (!ok) __builtin_amdgcn_s_sleep(2);
        } while (!ok && ++it < SPIN_MAX);
      }
      BAR_LGKM();     // drains x ds_writes for all waves, then releases the block
    } else {
#pragma unroll
      for (int q = 0; q < 3; ++q)
        __builtin_nontemporal_store(hn[q],
            out + ((size_t)eb * TS + t_in) * 1536 + dir * HU + u0 + ep + 8 * q);
    }
  }
}

extern "C" void kernel_launch(void* const* d_in, const int* in_sizes, int n_in,
                              void* d_out, int out_size, void* d_ws, size_t ws_size,
                              hipStream_t stream) {
  const float* x   = (const float*)d_in[0];
  const float* Wfw = (const float*)d_in[1];
  const float* bfw = (const float*)d_in[2];
  const float* pfw = (const float*)d_in[3];
  const float* Wbw = (const float*)d_in[4];
  const float* bbw = (const float*)d_in[5];
  const float* pbw = (const float*)d_in[6];
  float* out = (float*)d_out;

  char* ws = (char*)d_ws;
  unsigned short* xh   = (unsigned short*)ws;                       // 33,554,432 B
  unsigned short* hbfw = (unsigned short*)(ws + 33554432);          //     98,304 B (2 bufs)
  unsigned short* hbbw = (unsigned short*)(ws + 33554432 + 98304);  //     98,304 B
  u32* ctrl            = (u32*)(ws + 33554432 + 2 * 98304);         //      2,048 B

  lstm_init_k<<<99, 256, 0, stream>>>((u32*)hbfw, (u32*)hbbw, ctrl);
  lstm_xpose_k<<<16384, 256, 0, stream>>>(x, xh);
  lstm_persist_k<<<dim3(2 * NWG), dim3(256), 0, stream>>>(Wfw, bfw, pfw, Wbw, bbw, pbw,
                                                          xh, hbfw, hbbw, ctrl, out);
}

// Round 8
// 5862.130 us; speedup vs baseline: 1.6652x; 1.2097x over previous
//
#include <hip/hip_runtime.h>
#include <stdint.h>

#define TS   1024
#define NB   32
#define DIN  512
#define HU   768
#define NWG  32          // workgroups per direction
#define UPW  24          // hidden units per WG
#define XPAD 520         // x LDS row stride in fp16 (512+8: bank-phase stagger)
#define HPAD 776         // h LDS row stride in fp16 (768+8: bank-phase stagger)
#define SPIN_MAX 16384

typedef _Float16 f16x8 __attribute__((ext_vector_type(8)));
typedef float f32x16 __attribute__((ext_vector_type(16)));
typedef unsigned int u32;
typedef unsigned long long u64;
typedef u32 u32x4 __attribute__((ext_vector_type(4)));

__device__ __forceinline__ u32 f2h_bits(float f) {
  _Float16 h = (_Float16)f;
  return (u32)__builtin_bit_cast(unsigned short, h);
}

// ---- init: zero 2 dirs x 2 slots x 8192 u64 (tags=0 == step-0 ready; replay-safe) ----
__global__ void lstm_init_k(u64* hb) {
  hb[blockIdx.x * 256 + threadIdx.x] = 0ull;   // grid 128 x 256 = 32768 u64
}

// ---- transpose + fp16 convert: x[B][T][D] -> xh[T][B][D] ----
__global__ void lstm_xpose_k(const float* __restrict__ x, unsigned short* __restrict__ xh) {
  int idx = blockIdx.x * 256 + threadIdx.x;
  int d4 = idx & 127;
  int t  = (idx >> 7) & 1023;
  int b  = idx >> 17;
  float4 v = *(const float4*)(x + ((size_t)(b * TS + t) * DIN + d4 * 4));
  ushort4 o;
  o.x = (unsigned short)f2h_bits(v.x); o.y = (unsigned short)f2h_bits(v.y);
  o.z = (unsigned short)f2h_bits(v.z); o.w = (unsigned short)f2h_bits(v.w);
  *(ushort4*)(xh + ((size_t)(t * NB + b) * DIN + d4 * 4)) = o;
}

#define BAR_LGKM() do { asm volatile("s_waitcnt lgkmcnt(0)" ::: "memory"); \
  __builtin_amdgcn_sched_barrier(0); __builtin_amdgcn_s_barrier(); \
  __builtin_amdgcn_sched_barrier(0); } while (0)

// ---- persistent bidirectional LSTM scan (64 blocks, tagged-word sync, no barriers/flags) ----
__global__ __launch_bounds__(256, 1) void lstm_persist_k(
    const float* __restrict__ Wfw, const float* __restrict__ bfw, const float* __restrict__ pfw,
    const float* __restrict__ Wbw, const float* __restrict__ bbw, const float* __restrict__ pbw,
    const unsigned short* __restrict__ xh,
    u64* hb, float* __restrict__ out)
{
  __shared__ __align__(16) unsigned short As[NB * XPAD];   // 33,280 B (x tile)
  __shared__ __align__(16) unsigned short Hs[NB * HPAD];   // 49,664 B (h tile)
  __shared__ __align__(16) float Zs[4][NB][100];           // 51,200 B

  const int tid = threadIdx.x;
  const int dir = (blockIdx.x >= NWG) ? 1 : 0;
  const int gg  = blockIdx.x & (NWG - 1);

  const float* W    = dir ? Wbw : Wfw;
  const float* bias = dir ? bbw : bfw;
  const float* peep = dir ? pbw : pfw;
  u64* hslot = hb + (size_t)dir * 2 * 8192;   // [2 slots][8192 words]
  const int u0 = gg * UPW;

  const int lane  = tid & 63;
  const int wq    = tid >> 6;      // wave id
  const int colc  = lane & 31;
  const int khalf = lane >> 5;
  const int arow  = colc;          // A-frag row = batch
  const int eb    = tid >> 3;      // epilogue batch row
  const int ep    = tid & 7;       // epilogue phase

  // ---- preload W: 3 col-tiles x 20 K-slices; K-stripe c = 8m + 4*khalf + wq ----
  // tile ct, local col j: gate = j&3, unit = u0 + 8*ct + (j>>2)
  f16x8 wfr[3][20];
#pragma unroll
  for (int ct = 0; ct < 3; ++ct) {
    const int gcol = (colc & 3) * HU + u0 + 8 * ct + (colc >> 2);
#pragma unroll
    for (int m = 0; m < 20; ++m) {
      const int k0 = (8 * m + 4 * khalf + wq) * 8;
#pragma unroll
      for (int j = 0; j < 8; ++j)
        wfr[ct][m][j] = (_Float16)W[(size_t)(k0 + j) * 3072 + gcol];
    }
  }

  // ---- epilogue constants: 3 CONTIGUOUS units U = u0 + 3*ep + q ----
  float bi[3], bj[3], bfc[3], bo[3], pi[3], pfc[3], po[3], cst[3];
#pragma unroll
  for (int q = 0; q < 3; ++q) {
    const int U = u0 + 3 * ep + q;
    bi[q] = bias[U]; bj[q] = bias[HU + U]; bfc[q] = bias[2 * HU + U]; bo[q] = bias[3 * HU + U];
    pi[q] = peep[U]; pfc[q] = peep[HU + U]; po[q] = peep[2 * HU + U];
    cst[q] = 0.0f;
  }

  // ---- prologue: x(t0) -> LDS ----
  {
    const unsigned short* x0 = xh + (size_t)(dir ? (TS - 1) : 0) * (NB * DIN);
    u32x4 t[8];
#pragma unroll
    for (int k = 0; k < 8; ++k) t[k] = *(const u32x4*)(x0 + (tid + 256 * k) * 8);
#pragma unroll
    for (int k = 0; k < 8; ++k) {
      const int idx = tid + 256 * k;
      *(u32x4*)(&As[(idx >> 6) * XPAD + (idx & 63) * 8]) = t[k];
    }
  }
  BAR_LGKM();

  u32x4 xr[8];   // x prefetch regs for step s+1

  for (int s = 0; s < TS; ++s) {
    const int t_in = dir ? (TS - 1 - s) : s;
    const u32 tag = (u32)s;
    const char* hp = (const char*)(hslot + (size_t)(s & 1) * 8192) + 16 * tid;
    u64* hdst = hslot + (size_t)((s + 1) & 1) * 8192;

    // ---- A: issue tagged h(s) loads — lane-stride 16B, fully coalesced ----
    u32x4 hw[16];
#pragma unroll
    for (int k = 0; k < 16; ++k)
      asm volatile("global_load_dwordx4 %0, %1, off sc0 sc1"
                   : "=v"(hw[k]) : "v"(hp + 4096 * k) : "memory");

    // ---- A2: x(s+1) prefetch (plain cached; arrives before the vmcnt(0) below) ----
    if (s + 1 < TS) {
      const unsigned short* xnb = xh + (size_t)(dir ? (TS - 2 - s) : (s + 1)) * (NB * DIN);
#pragma unroll
      for (int k = 0; k < 8; ++k) xr[k] = *(const u32x4*)(xnb + (tid + 256 * k) * 8);
    }

    // ---- B: x-tile MFMAs (LDS, staged last step) hide the h-load round trip ----
    f32x16 a0, a1, a2;
#pragma unroll
    for (int r = 0; r < 16; ++r) { a0[r] = 0.f; a1[r] = 0.f; a2[r] = 0.f; }
#pragma unroll
    for (int m = 0; m < 8; ++m) {
      const int c = 8 * m + 4 * khalf + wq;
      const f16x8 av = *(const f16x8*)(&As[arow * XPAD + c * 8]);
      a0 = __builtin_amdgcn_mfma_f32_32x32x16_f16(av, wfr[0][m], a0, 0, 0, 0);
      a1 = __builtin_amdgcn_mfma_f32_32x32x16_f16(av, wfr[1][m], a1, 0, 0, 0);
      a2 = __builtin_amdgcn_mfma_f32_32x32x16_f16(av, wfr[2][m], a2, 0, 0, 0);
    }

    // ---- C: tag check + bounded retry (each wave independent) ----
    {
      int it = 0;
      while (true) {
        asm volatile("s_waitcnt vmcnt(0)" ::: "memory");
        __builtin_amdgcn_sched_barrier(0);             // rule #18: pin hw uses after waitcnt
        u32 bad = 0;
#pragma unroll
        for (int k = 0; k < 16; ++k)
          bad |= ((hw[k][1] >> 16) ^ tag) | ((hw[k][3] >> 16) ^ tag);
        if (__all((int)(bad == 0)) || ++it >= SPIN_MAX) break;
        if (it > 16) __builtin_amdgcn_s_sleep(1);
#pragma unroll
        for (int k = 0; k < 16; ++k)
          asm volatile("global_load_dwordx4 %0, %1, off sc0 sc1"
                       : "=v"(hw[k]) : "v"(hp + 4096 * k) : "memory");
      }
    }

    // ---- D: unpack {3 fp16 + tag}x2 per 16B -> Hs (12B/lane stride, <=2-way banks) ----
    {
      char* dp0 = (char*)Hs + (size_t)(tid >> 7) * (2 * HPAD) + 12 * (tid & 127);
#pragma unroll
      for (int k = 0; k < 16; ++k) {
        const u32 xw = hw[k][0], yw = hw[k][1], zw = hw[k][2], ww = hw[k][3];
        char* dp = dp0 + k * (4 * HPAD);               // 2 rows per k
        *(u32*)(dp)     = xw;
        *(u32*)(dp + 4) = (yw & 0xFFFFu) | (zw << 16);
        *(u32*)(dp + 8) = (zw >> 16) | (ww << 16);
      }
    }
    BAR_LGKM();   // Hs complete; all As x-reads done (program order per wave)

    // ---- E: h-tile MFMAs ----
#pragma unroll
    for (int m = 8; m < 20; ++m) {
      const int c = 8 * m + 4 * khalf + wq;
      const f16x8 av = *(const f16x8*)((char*)Hs + arow * (2 * HPAD) + (c - 64) * 16);
      a0 = __builtin_amdgcn_mfma_f32_32x32x16_f16(av, wfr[0][m], a0, 0, 0, 0);
      a1 = __builtin_amdgcn_mfma_f32_32x32x16_f16(av, wfr[1][m], a1, 0, 0, 0);
      a2 = __builtin_amdgcn_mfma_f32_32x32x16_f16(av, wfr[2][m], a2, 0, 0, 0);
    }

    // ---- F: partial z -> LDS; C/D layout: col=lane&31, row=(r&3)+8*(r>>2)+4*khalf ----
#pragma unroll
    for (int r = 0; r < 16; ++r) {
      const int prow = (r & 3) + 8 * (r >> 2) + 4 * khalf;
      Zs[wq][prow][colc]      = a0[r];
      Zs[wq][prow][32 + colc] = a1[r];
      Zs[wq][prow][64 + colc] = a2[r];
    }
    // ---- F2: staged x(s+1) regs -> As (x-reads finished before barrier above) ----
    if (s + 1 < TS) {
#pragma unroll
      for (int k = 0; k < 8; ++k) {
        const int idx = tid + 256 * k;
        *(u32x4*)(&As[(idx >> 6) * XPAD + (idx & 63) * 8]) = xr[k];
      }
    }
    BAR_LGKM();   // Zs ready; As restaged

    // ---- G: epilogue, 3 contiguous cells (row eb, units u0+3ep+q) ----
    float hn[3];
#pragma unroll
    for (int q = 0; q < 3; ++q) {
      const int uu = 3 * ep + q;
      float zi = 0.f, zj = 0.f, zf = 0.f, zo = 0.f;
#pragma unroll
      for (int qq = 0; qq < 4; ++qq) {
        const float4 zp = *(const float4*)(&Zs[qq][eb][uu * 4]);
        zi += zp.x; zj += zp.y; zf += zp.z; zo += zp.w;
      }
      const float ig = 1.f / (1.f + __expf(-(zi + bi[q] + pi[q] * cst[q])));
      const float fg = 1.f / (1.f + __expf(-(zf + bfc[q] + 1.f + pfc[q] * cst[q])));
      const float jt = 1.f - 2.f / (__expf(2.f * (zj + bj[q])) + 1.f);
      const float cn = fg * cst[q] + ig * jt;
      const float og = 1.f / (1.f + __expf(-(zo + bo[q] + po[q] * cn)));
      hn[q] = og * (1.f - 2.f / (__expf(2.f * cn) + 1.f));
      cst[q] = cn;
    }

    // ---- H: publish h(s+1) as ONE tagged 8B store (fire-and-forget, no ordering wait) ----
    if (s < TS - 1) {
      const u64 pk = (u64)f2h_bits(hn[0])
                   | ((u64)f2h_bits(hn[1]) << 16)
                   | ((u64)f2h_bits(hn[2]) << 32)
                   | ((u64)(u32)(s + 1) << 48);
      __hip_atomic_store(hdst + eb * 256 + 8 * gg + ep, pk,
                         __ATOMIC_RELAXED, __HIP_MEMORY_SCOPE_AGENT);
    }

    // ---- out stores (plain, L2-acked; overlap next step's h-load RT) ----
    {
      float* op = out + ((size_t)eb * TS + t_in) * 1536 + dir * HU + u0 + 3 * ep;
      __builtin_nontemporal_store(hn[0], op);
      __builtin_nontemporal_store(hn[1], op + 1);
      __builtin_nontemporal_store(hn[2], op + 2);
    }
  }
}

extern "C" void kernel_launch(void* const* d_in, const int* in_sizes, int n_in,
                              void* d_out, int out_size, void* d_ws, size_t ws_size,
                              hipStream_t stream) {
  const float* x   = (const float*)d_in[0];
  const float* Wfw = (const float*)d_in[1];
  const float* bfw = (const float*)d_in[2];
  const float* pfw = (const float*)d_in[3];
  const float* Wbw = (const float*)d_in[4];
  const float* bbw = (const float*)d_in[5];
  const float* pbw = (const float*)d_in[6];
  float* out = (float*)d_out;

  char* ws = (char*)d_ws;
  unsigned short* xh = (unsigned short*)ws;              // 33,554,432 B
  u64* hb            = (u64*)(ws + 33554432);            //    262,144 B (2 dir x 2 slot x 64 KB)

  lstm_init_k<<<128, 256, 0, stream>>>(hb);
  lstm_xpose_k<<<16384, 256, 0, stream>>>(x, xh);
  lstm_persist_k<<<dim3(2 * NWG), dim3(256), 0, stream>>>(Wfw, bfw, pfw, Wbw, bbw, pbw,
                                                          xh, hb, out);
}